// Round 1
// baseline (1042.486 us; speedup 1.0000x reference)
//
#include <hip/hip_runtime.h>
#include <hip/hip_bf16.h>

#define B_  512
#define S_  196
#define D_  1024
#define A_  512
#define O_  1000

typedef __attribute__((ext_vector_type(8))) __bf16 bf16x8_t;
typedef __attribute__((ext_vector_type(4))) float f32x4;

__device__ __forceinline__ unsigned short f2bf(float f) {
    union { float f; unsigned u; } v; v.f = f;
    unsigned r = v.u + 0x7FFFu + ((v.u >> 16) & 1u);   // RNE
    return (unsigned short)(r >> 16);
}

// ---------------- Wi [D][A] f32 -> WiT [A][D] bf16 ----------------
__global__ void transpose_to_bf16(const float* __restrict__ Wi,
                                  unsigned short* __restrict__ WiT) {
    __shared__ float tile[32][33];
    int bd = blockIdx.x;            // 32 d-tiles
    int ba = blockIdx.y;            // 16 a-tiles
    int tx = threadIdx.x & 31, ty = threadIdx.x >> 5;
    #pragma unroll
    for (int r = ty; r < 32; r += 8)
        tile[r][tx] = Wi[(bd * 32 + r) * A_ + ba * 32 + tx];
    __syncthreads();
    #pragma unroll
    for (int r = ty; r < 32; r += 8)
        WiT[(ba * 32 + r) * D_ + bd * 32 + tx] = f2bf(tile[tx][r]);
}

// ---------------- qe = q @ W + bias ; 8 b-rows per block ----------------
__global__ void qproj(const float* __restrict__ q, const float* __restrict__ W,
                      const float* __restrict__ bias, float* __restrict__ qe) {
    __shared__ float qs[8][D_];
    int b0 = blockIdx.x * 8;
    int a  = blockIdx.y * 256 + threadIdx.x;
    for (int i = threadIdx.x; i < 8 * D_; i += 256)
        qs[i >> 10][i & 1023] = q[(b0 + (i >> 10)) * D_ + (i & 1023)];
    __syncthreads();
    float acc[8];
    float bb = bias[a];
    #pragma unroll
    for (int j = 0; j < 8; ++j) acc[j] = bb;
    #pragma unroll 4
    for (int d = 0; d < D_; ++d) {
        float w = W[d * A_ + a];
        #pragma unroll
        for (int j = 0; j < 8; ++j) acc[j] += qs[j][d] * w;
    }
    #pragma unroll
    for (int j = 0; j < 8; ++j) qe[(b0 + j) * A_ + a] = acc[j];
}

// ---------------- fused: scores[b,s] = Ws . tanh(qe[b] + img[b,s]@Wi) ----------------
#define MT 64
#define KT 32
#define LDA 40   // padded LDS stride in bf16 units (80B -> 2-way conflicts only)

__global__ __launch_bounds__(512)
void score_kernel(const float* __restrict__ img,
                  const unsigned short* __restrict__ WiT,   // [A_][D_] bf16
                  const float* __restrict__ qe,             // [B_][A_]
                  const float* __restrict__ Ws,             // [A_]
                  float* __restrict__ scores)               // [B_*S_]
{
    __shared__ __align__(16) unsigned short Asmem[MT][LDA];   // 5 KB
    __shared__ __align__(16) unsigned short Bsmem[A_][LDA];   // 40 KB
    __shared__ float ws_s[A_];
    __shared__ float qe_s[2][A_];
    __shared__ float score_s[MT];

    int tid  = threadIdx.x;
    int lane = tid & 63;
    int wave = tid >> 6;       // 0..7
    int wm   = wave >> 2;      // 0..1  (rows)
    int wn   = wave & 3;       // 0..3  (cols)

    long row0 = (long)blockIdx.x * MT;
    int  b0   = (int)(row0 / S_);
    long b0s  = (long)b0 * S_;

    // stage Ws / qe rows (tile spans at most 2 b's since MT < S_)
    if (tid < A_) {
        ws_s[tid]    = Ws[tid];
        qe_s[0][tid] = qe[b0 * A_ + tid];
        qe_s[1][tid] = (b0 + 1 < B_) ? qe[(b0 + 1) * A_ + tid] : 0.f;
    }
    if (tid < MT) score_s[tid] = 0.f;

    f32x4 acc[2][8];
    #pragma unroll
    for (int m = 0; m < 2; ++m)
        #pragma unroll
        for (int n = 0; n < 8; ++n) acc[m][n] = (f32x4)0.f;

    #pragma unroll 1
    for (int k0 = 0; k0 < D_; k0 += KT) {
        __syncthreads();
        // stage A: 64 rows x 32 k, f32 -> bf16
        {
            int r = tid >> 3, c = (tid & 7) * 4;
            float4 v = *reinterpret_cast<const float4*>(&img[(row0 + r) * D_ + k0 + c]);
            unsigned lo = (unsigned)f2bf(v.x) | ((unsigned)f2bf(v.y) << 16);
            unsigned hi = (unsigned)f2bf(v.z) | ((unsigned)f2bf(v.w) << 16);
            *reinterpret_cast<uint2*>(&Asmem[r][c]) = make_uint2(lo, hi);
        }
        // stage B^T: 512 a-rows x 32 k bf16 from WiT
        #pragma unroll
        for (int it = 0; it < 4; ++it) {
            int idx = tid + 512 * it;
            int a = idx >> 2, seg = idx & 3;
            uint4 v = *reinterpret_cast<const uint4*>(&WiT[a * D_ + k0 + seg * 8]);
            *reinterpret_cast<uint4*>(&Bsmem[a][seg * 8]) = v;
        }
        __syncthreads();

        bf16x8_t af[2];
        #pragma unroll
        for (int m = 0; m < 2; ++m) {
            int r = wm * 32 + m * 16 + (lane & 15);
            af[m] = *reinterpret_cast<const bf16x8_t*>(&Asmem[r][(lane >> 4) * 8]);
        }
        #pragma unroll
        for (int n = 0; n < 8; ++n) {
            int a = wn * 128 + n * 16 + (lane & 15);
            bf16x8_t bfv = *reinterpret_cast<const bf16x8_t*>(&Bsmem[a][(lane >> 4) * 8]);
            #pragma unroll
            for (int m = 0; m < 2; ++m)
                acc[m][n] = __builtin_amdgcn_mfma_f32_16x16x32_bf16(af[m], bfv, acc[m][n], 0, 0, 0);
        }
    }

    // epilogue: tanh(v + qe) weighted by Ws, reduce over all 512 cols
    float part[2][4];
    #pragma unroll
    for (int m = 0; m < 2; ++m)
        #pragma unroll
        for (int r = 0; r < 4; ++r) part[m][r] = 0.f;

    #pragma unroll
    for (int n = 0; n < 8; ++n) {
        int col = wn * 128 + n * 16 + (lane & 15);
        float w  = ws_s[col];
        float q0 = qe_s[0][col], q1 = qe_s[1][col];
        #pragma unroll
        for (int m = 0; m < 2; ++m) {
            int rbase = wm * 32 + m * 16 + ((lane >> 4) << 2);
            #pragma unroll
            for (int r = 0; r < 4; ++r) {
                long rowg = row0 + rbase + r;
                float qv = ((rowg - b0s) >= S_) ? q1 : q0;
                float x = acc[m][n][r] + qv;
                float e = __expf(2.f * x);
                float h = 1.f - 2.f / (e + 1.f);      // tanh, saturates cleanly at +-1
                part[m][r] += w * h;
            }
        }
    }

    #pragma unroll
    for (int m = 0; m < 2; ++m)
        #pragma unroll
        for (int r = 0; r < 4; ++r) {
            float v = part[m][r];
            v += __shfl_xor(v, 1);
            v += __shfl_xor(v, 2);
            v += __shfl_xor(v, 4);
            v += __shfl_xor(v, 8);
            if ((lane & 15) == 0)
                atomicAdd(&score_s[wm * 32 + m * 16 + ((lane >> 4) << 2) + r], v);
        }
    __syncthreads();
    if (tid < MT) scores[row0 + tid] = score_s[tid];
}

// ---------------- softmax over S=196 per row ----------------
__global__ void softmax196(float* __restrict__ sc) {
    int b = blockIdx.x, t = threadIdx.x;
    __shared__ float wred[4];
    float v = (t < S_) ? sc[b * S_ + t] : -1e30f;
    float m = v;
    #pragma unroll
    for (int o = 1; o < 64; o <<= 1) m = fmaxf(m, __shfl_xor(m, o));
    if ((t & 63) == 0) wred[t >> 6] = m;
    __syncthreads();
    m = fmaxf(fmaxf(wred[0], wred[1]), fmaxf(wred[2], wred[3]));
    float e = (t < S_) ? __expf(v - m) : 0.f;
    float s = e;
    #pragma unroll
    for (int o = 1; o < 64; o <<= 1) s += __shfl_xor(s, o);
    __syncthreads();
    if ((t & 63) == 0) wred[t >> 6] = s;
    __syncthreads();
    s = wred[0] + wred[1] + wred[2] + wred[3];
    if (t < S_) sc[b * S_ + t] = e / s;
}

// ---------------- u = qin + sum_s p[b,s]*img[b,s,:] ----------------
__global__ void pool_add(const float* __restrict__ p, const float* __restrict__ img,
                         const float* __restrict__ qin, float* __restrict__ uout) {
    __shared__ float ps[S_];
    int b = blockIdx.x, d = blockIdx.y * 256 + threadIdx.x;
    if (threadIdx.x < S_) ps[threadIdx.x] = p[b * S_ + threadIdx.x];
    __syncthreads();
    float acc = 0.f;
    const float* ib = &img[(long)b * S_ * D_ + d];
    #pragma unroll 4
    for (int s = 0; s < S_; ++s) acc += ps[s] * ib[(long)s * D_];
    uout[b * D_ + d] = qin[b * D_ + d] + acc;
}

// ---------------- out = u @ Wfc + bfc ; 8 b-rows per block ----------------
__global__ void fcout(const float* __restrict__ u, const float* __restrict__ W,
                      const float* __restrict__ bias, float* __restrict__ out) {
    __shared__ float us[8][D_];
    int b0 = blockIdx.x * 8;
    int o  = blockIdx.y * 256 + threadIdx.x;
    for (int i = threadIdx.x; i < 8 * D_; i += 256)
        us[i >> 10][i & 1023] = u[(b0 + (i >> 10)) * D_ + (i & 1023)];
    __syncthreads();
    if (o < O_) {
        float acc[8];
        float bb = bias[o];
        #pragma unroll
        for (int j = 0; j < 8; ++j) acc[j] = bb;
        #pragma unroll 4
        for (int d = 0; d < D_; ++d) {
            float w = W[d * O_ + o];
            #pragma unroll
            for (int j = 0; j < 8; ++j) acc[j] += us[j][d] * w;
        }
        #pragma unroll
        for (int j = 0; j < 8; ++j) out[(b0 + j) * O_ + o] = acc[j];
    }
}

extern "C" void kernel_launch(void* const* d_in, const int* in_sizes, int n_in,
                              void* d_out, int out_size, void* d_ws, size_t ws_size,
                              hipStream_t stream) {
    (void)in_sizes; (void)n_in; (void)out_size; (void)ws_size;
    const float* ques = (const float*)d_in[0];
    const float* img  = (const float*)d_in[1];
    const float* W11  = (const float*)d_in[2];
    const float* b11  = (const float*)d_in[3];
    const float* W12  = (const float*)d_in[4];
    const float* W13  = (const float*)d_in[5];
    // d_in[6] = b13: softmax-invariant, unused
    const float* W21  = (const float*)d_in[7];
    const float* b21  = (const float*)d_in[8];
    const float* W22  = (const float*)d_in[9];
    const float* W23  = (const float*)d_in[10];
    // d_in[11] = b23: softmax-invariant, unused
    const float* Wfc  = (const float*)d_in[12];
    const float* bfc  = (const float*)d_in[13];
    float* out = (float*)d_out;

    char* ws = (char*)d_ws;
    unsigned short* WiT = (unsigned short*)ws; ws += (size_t)A_ * D_ * 2;  // 1 MB
    float* qe = (float*)ws; ws += (size_t)B_ * A_ * 4;                     // 1 MB
    float* sc = (float*)ws; ws += (size_t)B_ * S_ * 4;                     // 392 KB
    float* u1 = (float*)ws; ws += (size_t)B_ * D_ * 4;                     // 2 MB
    float* u2 = (float*)ws;                                                // 2 MB

    int nscore = (B_ * S_) / MT;   // 1568

    // hop 1
    transpose_to_bf16<<<dim3(32, 16), 256, 0, stream>>>(W12, WiT);
    qproj<<<dim3(B_ / 8, A_ / 256), 256, 0, stream>>>(ques, W11, b11, qe);
    score_kernel<<<dim3(nscore), 512, 0, stream>>>(img, WiT, qe, W13, sc);
    softmax196<<<dim3(B_), 256, 0, stream>>>(sc);
    pool_add<<<dim3(B_, D_ / 256), 256, 0, stream>>>(sc, img, ques, u1);

    // hop 2 (reuse WiT buffer; stream-ordered after score_kernel hop 1)
    transpose_to_bf16<<<dim3(32, 16), 256, 0, stream>>>(W22, WiT);
    qproj<<<dim3(B_ / 8, A_ / 256), 256, 0, stream>>>(u1, W21, b21, qe);
    score_kernel<<<dim3(nscore), 512, 0, stream>>>(img, WiT, qe, W23, sc);
    softmax196<<<dim3(B_), 256, 0, stream>>>(sc);
    pool_add<<<dim3(B_, D_ / 256), 256, 0, stream>>>(sc, img, u1, u2);

    // final FC
    fcout<<<dim3(B_ / 8, (O_ + 255) / 256), 256, 0, stream>>>(u2, Wfc, bfc, out);
}

// Round 2
// 880.068 us; speedup vs baseline: 1.1846x; 1.1846x over previous
//
#include <hip/hip_runtime.h>
#include <hip/hip_bf16.h>

#define B_  512
#define S_  196
#define D_  1024
#define A_  512
#define O_  1000

typedef __attribute__((ext_vector_type(8))) __bf16 bf16x8_t;
typedef __attribute__((ext_vector_type(16))) float f32x16;

__device__ __forceinline__ unsigned short f2bf(float f) {
    union { float f; unsigned u; } v; v.f = f;
    unsigned r = v.u + 0x7FFFu + ((v.u >> 16) & 1u);   // RNE
    return (unsigned short)(r >> 16);
}

// ---- pack Wi [D][A] f32 -> Bp fragment-linear bf16: [nfrag(16)][ks(64)][lane(64)][8]
__global__ void bpack(const float* __restrict__ Wi, unsigned short* __restrict__ Bp) {
    int n = blockIdx.x, ks = blockIdx.y, l = threadIdx.x;
    int a  = n * 32 + (l & 31);
    int kb = ks * 16 + (l >> 5) * 8;
    unsigned short o[8];
    #pragma unroll
    for (int e = 0; e < 8; ++e) o[e] = f2bf(Wi[(size_t)(kb + e) * A_ + a]);
    *reinterpret_cast<uint4*>(&Bp[((size_t)(n * 64 + ks) * 64 + l) * 8]) =
        *reinterpret_cast<const uint4*>(o);
}

// ---- qe = q @ W + bias ; 4 rows per block, 256 blocks total
__global__ void qproj(const float* __restrict__ q, const float* __restrict__ W,
                      const float* __restrict__ bias, float* __restrict__ qe) {
    __shared__ float qs[4][D_];
    int b0 = blockIdx.x * 4;
    int a  = blockIdx.y * 256 + threadIdx.x;
    for (int i = threadIdx.x; i < 4 * D_; i += 256)
        qs[i >> 10][i & 1023] = q[(b0 + (i >> 10)) * D_ + (i & 1023)];
    __syncthreads();
    float acc[4];
    float bb = bias[a];
    #pragma unroll
    for (int j = 0; j < 4; ++j) acc[j] = bb;
    #pragma unroll 4
    for (int d = 0; d < D_; ++d) {
        float w = W[d * A_ + a];
        #pragma unroll
        for (int j = 0; j < 4; ++j) acc[j] += qs[j][d] * w;
    }
    #pragma unroll
    for (int j = 0; j < 4; ++j) qe[(b0 + j) * A_ + a] = acc[j];
}

// ---- fused: scores[row] = Ws . tanh(qe[b] + img[row]@Wi), row = b*S+s
// 64 rows/block, 4 waves; wave tile 64x128 via 32x32x16 MFMA (m=2,n=4).
// B from L2 (fragment-packed) straight to VGPRs; A double-buffered in LDS,
// XOR-swizzled (slot^(row&7)) for conflict-floor ds_read_b128.
#define MT 64
#define KT 64

__global__ __launch_bounds__(256, 2)
void score_kernel(const float* __restrict__ img,
                  const unsigned short* __restrict__ Bp,
                  const float* __restrict__ qe,
                  const float* __restrict__ Ws,
                  float* __restrict__ scores)
{
    __shared__ __align__(16) unsigned short Asm[2][MT][KT];   // 16 KB
    __shared__ float ws_s[A_];
    __shared__ float qe_s[2][A_];
    __shared__ float score_s[MT];

    const int tid  = threadIdx.x;
    const int lane = tid & 63;
    const int wn   = tid >> 6;                 // 0..3: col slice of 128
    const long row0 = (long)blockIdx.x * MT;
    const int  b0   = (int)(row0 / S_);
    const long b0s  = (long)b0 * S_;

    for (int i = tid; i < A_; i += 256) {
        ws_s[i]    = Ws[i];
        qe_s[0][i] = qe[b0 * A_ + i];
        qe_s[1][i] = (b0 + 1 < B_) ? qe[(b0 + 1) * A_ + i] : 0.f;
    }
    if (tid < MT) score_s[tid] = 0.f;

    f32x16 acc[2][4];
    #pragma unroll
    for (int m = 0; m < 2; ++m)
        #pragma unroll
        for (int n = 0; n < 4; ++n) acc[m][n] = (f32x16)0.f;

    const int srow = tid >> 2;                 // staging row 0..63
    const int sseg = (tid & 3) * 2;            // logical slot {0,2,4,6}
    const float* gsrc = &img[(size_t)(row0 + srow) * D_ + sseg * 8];

    auto STAGE = [&](int buf, int t) {
        const float* g = gsrc + t * KT;
        float4 v0 = *reinterpret_cast<const float4*>(g);
        float4 v1 = *reinterpret_cast<const float4*>(g + 4);
        float4 v2 = *reinterpret_cast<const float4*>(g + 8);
        float4 v3 = *reinterpret_cast<const float4*>(g + 12);
        uint4 u0, u1;
        u0.x = (unsigned)f2bf(v0.x) | ((unsigned)f2bf(v0.y) << 16);
        u0.y = (unsigned)f2bf(v0.z) | ((unsigned)f2bf(v0.w) << 16);
        u0.z = (unsigned)f2bf(v1.x) | ((unsigned)f2bf(v1.y) << 16);
        u0.w = (unsigned)f2bf(v1.z) | ((unsigned)f2bf(v1.w) << 16);
        u1.x = (unsigned)f2bf(v2.x) | ((unsigned)f2bf(v2.y) << 16);
        u1.y = (unsigned)f2bf(v2.z) | ((unsigned)f2bf(v2.w) << 16);
        u1.z = (unsigned)f2bf(v3.x) | ((unsigned)f2bf(v3.y) << 16);
        u1.w = (unsigned)f2bf(v3.z) | ((unsigned)f2bf(v3.w) << 16);
        *reinterpret_cast<uint4*>(&Asm[buf][srow][((sseg    ) ^ (srow & 7)) * 8]) = u0;
        *reinterpret_cast<uint4*>(&Asm[buf][srow][((sseg + 1) ^ (srow & 7)) * 8]) = u1;
    };

    STAGE(0, 0);
    __syncthreads();

    const bf16x8_t* Bpv = reinterpret_cast<const bf16x8_t*>(Bp);

    for (int t = 0; t < D_ / KT; ++t) {
        const int cur = t & 1;
        if (t + 1 < D_ / KT) STAGE(cur ^ 1, t + 1);   // prefetch next A-tile
        #pragma unroll
        for (int ks = 0; ks < 4; ++ks) {
            bf16x8_t bfr[4], afr[2];
            #pragma unroll
            for (int n = 0; n < 4; ++n)
                bfr[n] = Bpv[((size_t)((wn * 4 + n) * 64 + (t * 4 + ks))) * 64 + lane];
            #pragma unroll
            for (int m = 0; m < 2; ++m) {
                int r = m * 32 + (lane & 31);
                int slot = (ks * 2 + (lane >> 5)) ^ (r & 7);
                afr[m] = *reinterpret_cast<const bf16x8_t*>(&Asm[cur][r][slot * 8]);
            }
            #pragma unroll
            for (int m = 0; m < 2; ++m)
                #pragma unroll
                for (int n = 0; n < 4; ++n)
                    acc[m][n] = __builtin_amdgcn_mfma_f32_32x32x16_bf16(
                        afr[m], bfr[n], acc[m][n], 0, 0, 0);
        }
        __syncthreads();
    }

    // epilogue: part[m][reg] = sum over this wave's 128 cols of Ws*tanh(v+qe)
    float part[2][16];
    #pragma unroll
    for (int m = 0; m < 2; ++m)
        #pragma unroll
        for (int rg = 0; rg < 16; ++rg) part[m][rg] = 0.f;

    #pragma unroll
    for (int n = 0; n < 4; ++n) {
        int col = wn * 128 + n * 32 + (lane & 31);
        float w  = ws_s[col];
        float q0 = qe_s[0][col], q1 = qe_s[1][col];
        #pragma unroll
        for (int m = 0; m < 2; ++m) {
            #pragma unroll
            for (int rg = 0; rg < 16; ++rg) {
                int rl = m * 32 + (rg & 3) + ((rg >> 2) << 3) + ((lane >> 5) << 2);
                float qv = ((row0 + rl - b0s) >= S_) ? q1 : q0;
                float x = acc[m][n][rg] + qv;
                float e = __expf(2.f * x);
                part[m][rg] += w * (1.f - 2.f / (e + 1.f));   // w * tanh(x)
            }
        }
    }
    #pragma unroll
    for (int m = 0; m < 2; ++m)
        #pragma unroll
        for (int rg = 0; rg < 16; ++rg) {
            float v = part[m][rg];
            v += __shfl_xor(v, 1);
            v += __shfl_xor(v, 2);
            v += __shfl_xor(v, 4);
            v += __shfl_xor(v, 8);
            v += __shfl_xor(v, 16);
            if ((lane & 31) == 0) {
                int rl = m * 32 + (rg & 3) + ((rg >> 2) << 3) + ((lane >> 5) << 2);
                atomicAdd(&score_s[rl], v);
            }
        }
    __syncthreads();
    if (tid < MT) scores[row0 + tid] = score_s[tid];
}

// ---- fused softmax(196) + weighted pool + residual: u = qin + softmax(sc) @ img
__global__ void softpool(const float* __restrict__ sc, const float* __restrict__ img,
                         const float* __restrict__ qin, float* __restrict__ uout) {
    __shared__ float ps[S_];
    __shared__ float red1[4], red2[4];
    int b = blockIdx.x, t = threadIdx.x;
    int lane = t & 63, w = t >> 6;
    float v = (t < S_) ? sc[b * S_ + t] : -1e30f;
    float m = v;
    #pragma unroll
    for (int o = 1; o < 64; o <<= 1) m = fmaxf(m, __shfl_xor(m, o));
    if (lane == 0) red1[w] = m;
    __syncthreads();
    m = fmaxf(fmaxf(red1[0], red1[1]), fmaxf(red1[2], red1[3]));
    float e = (t < S_) ? __expf(v - m) : 0.f;
    float s = e;
    #pragma unroll
    for (int o = 1; o < 64; o <<= 1) s += __shfl_xor(s, o);
    if (lane == 0) red2[w] = s;
    __syncthreads();
    s = red2[0] + red2[1] + red2[2] + red2[3];
    if (t < S_) ps[t] = e / s;
    __syncthreads();

    int d0 = t * 4;
    const float* ib = &img[(size_t)b * S_ * D_ + d0];
    float a0 = 0.f, a1 = 0.f, a2 = 0.f, a3 = 0.f;
    #pragma unroll 2
    for (int sI = 0; sI < S_; ++sI) {
        float4 x = *reinterpret_cast<const float4*>(&ib[(size_t)sI * D_]);
        float p = ps[sI];
        a0 += p * x.x; a1 += p * x.y; a2 += p * x.z; a3 += p * x.w;
    }
    float4 q = *reinterpret_cast<const float4*>(&qin[(size_t)b * D_ + d0]);
    float4 o4 = make_float4(q.x + a0, q.y + a1, q.z + a2, q.w + a3);
    *reinterpret_cast<float4*>(&uout[(size_t)b * D_ + d0]) = o4;
}

// ---- out = u @ Wfc + bfc ; 4 rows per block
__global__ void fcout(const float* __restrict__ u, const float* __restrict__ W,
                      const float* __restrict__ bias, float* __restrict__ out) {
    __shared__ float us[4][D_];
    int b0 = blockIdx.x * 4;
    int o  = blockIdx.y * 256 + threadIdx.x;
    for (int i = threadIdx.x; i < 4 * D_; i += 256)
        us[i >> 10][i & 1023] = u[(b0 + (i >> 10)) * D_ + (i & 1023)];
    __syncthreads();
    if (o < O_) {
        float acc[4];
        float bb = bias[o];
        #pragma unroll
        for (int j = 0; j < 4; ++j) acc[j] = bb;
        #pragma unroll 4
        for (int d = 0; d < D_; ++d) {
            float w = W[d * O_ + o];
            #pragma unroll
            for (int j = 0; j < 4; ++j) acc[j] += us[j][d] * w;
        }
        #pragma unroll
        for (int j = 0; j < 4; ++j) out[(b0 + j) * O_ + o] = acc[j];
    }
}

extern "C" void kernel_launch(void* const* d_in, const int* in_sizes, int n_in,
                              void* d_out, int out_size, void* d_ws, size_t ws_size,
                              hipStream_t stream) {
    (void)in_sizes; (void)n_in; (void)out_size; (void)ws_size;
    const float* ques = (const float*)d_in[0];
    const float* img  = (const float*)d_in[1];
    const float* W11  = (const float*)d_in[2];
    const float* b11  = (const float*)d_in[3];
    const float* W12  = (const float*)d_in[4];
    const float* W13  = (const float*)d_in[5];
    // d_in[6] = b13: softmax-invariant, unused
    const float* W21  = (const float*)d_in[7];
    const float* b21  = (const float*)d_in[8];
    const float* W22  = (const float*)d_in[9];
    const float* W23  = (const float*)d_in[10];
    // d_in[11] = b23: softmax-invariant, unused
    const float* Wfc  = (const float*)d_in[12];
    const float* bfc  = (const float*)d_in[13];
    float* out = (float*)d_out;

    char* ws = (char*)d_ws;
    unsigned short* Bp1 = (unsigned short*)ws; ws += (size_t)A_ * D_ * 2;  // 1 MB
    unsigned short* Bp2 = (unsigned short*)ws; ws += (size_t)A_ * D_ * 2;  // 1 MB
    float* qe = (float*)ws; ws += (size_t)B_ * A_ * 4;                     // 1 MB
    float* sc = (float*)ws; ws += (size_t)B_ * S_ * 4;                     // 392 KB
    float* u1 = (float*)ws; ws += (size_t)B_ * D_ * 4;                     // 2 MB
    float* u2 = (float*)ws;                                                // 2 MB

    const int nscore = (B_ * S_) / MT;   // 1568

    // hop 1
    bpack<<<dim3(16, 64), 64, 0, stream>>>(W12, Bp1);
    qproj<<<dim3(B_ / 4, A_ / 256), 256, 0, stream>>>(ques, W11, b11, qe);
    score_kernel<<<dim3(nscore), 256, 0, stream>>>(img, Bp1, qe, W13, sc);
    softpool<<<dim3(B_), 256, 0, stream>>>(sc, img, ques, u1);

    // hop 2
    bpack<<<dim3(16, 64), 64, 0, stream>>>(W22, Bp2);
    qproj<<<dim3(B_ / 4, A_ / 256), 256, 0, stream>>>(u1, W21, b21, qe);
    score_kernel<<<dim3(nscore), 256, 0, stream>>>(img, Bp2, qe, W23, sc);
    softpool<<<dim3(B_), 256, 0, stream>>>(sc, img, u1, u2);

    // final FC
    fcout<<<dim3(B_ / 4, (O_ + 255) / 256), 256, 0, stream>>>(u2, Wfc, bfc, out);
}